// Round 9
// baseline (814.182 us; speedup 1.0000x reference)
//
#include <hip/hip_runtime.h>

#define NN 4096
#define HH 256
#define EE 131072

__device__ __constant__ float LN_EPS = 1e-5f;
#define ATT_SCALE 0.08838834764831845f
#define ATT_SHIFT 30.0f

typedef __attribute__((ext_vector_type(8))) short bf16x8_t;
typedef __attribute__((ext_vector_type(4))) float f32x4_t;

__device__ inline ushort f2b(float f) {
  uint u = __float_as_uint(f);
  uint r = (u + 0x7FFF + ((u >> 16) & 1)) >> 16;
  return (ushort)r;
}

// ---------------- CSR build ----------------
__global__ void hist_kernel(const int* __restrict__ ei, int* __restrict__ cnt) {
  int e = blockIdx.x * blockDim.x + threadIdx.x;
  if (e < EE) atomicAdd(&cnt[ei[EE + e]], 1);
}

__global__ __launch_bounds__(1024) void scan_kernel(int* __restrict__ cnt_cursor,
                                                    int* __restrict__ rowptr,
                                                    float* __restrict__ invdeg) {
  __shared__ int part[1024];
  int t = threadIdx.x;
  int base = t * 4;
  int cs[4];
  int s = 0;
  for (int u = 0; u < 4; ++u) { cs[u] = cnt_cursor[base + u]; s += cs[u]; }
  part[t] = s;
  __syncthreads();
  for (int off = 1; off < 1024; off <<= 1) {
    int add = (t >= off) ? part[t - off] : 0;
    int v = part[t];
    __syncthreads();
    part[t] = v + add;
    __syncthreads();
  }
  int excl = (t > 0) ? part[t - 1] : 0;
  for (int u = 0; u < 4; ++u) {
    rowptr[base + u] = excl;
    cnt_cursor[base + u] = excl;         // cursor for fill
    invdeg[base + u] = 1.0f / (float)max(cs[u], 1);
    excl += cs[u];
  }
  if (t == 1023) rowptr[NN] = excl;
}

__global__ void fill_kernel(const int* __restrict__ ei, int* __restrict__ cursor,
                            int* __restrict__ col) {
  int e = blockIdx.x * blockDim.x + threadIdx.x;
  if (e < EE) {
    int d = ei[EE + e];
    int p = atomicAdd(&cursor[d], 1);
    col[p] = ei[e];
  }
}

// ---------------- casts (R4-measured form: separate dispatches) ----------------
__global__ __launch_bounds__(256) void castw(const float* __restrict__ in,
                                             ushort* __restrict__ out) {
  int i4 = (blockIdx.x * 256 + threadIdx.x) * 4;
  float4 v = *(const float4*)(in + i4);
  ushort4 w;
  w.x = f2b(v.x); w.y = f2b(v.y); w.z = f2b(v.z); w.w = f2b(v.w);
  *(ushort4*)(out + i4) = w;
}

// conv weight repack: out[j][o][ks*256+ii] = w[j][o][ii][ks]
__global__ __launch_bounds__(256) void castconv(const float* __restrict__ w,
                                                ushort* __restrict__ o) {
  int idx = blockIdx.x * 256 + threadIdx.x;
  int j = idx / 196608;
  int rem = idx - j * 196608;
  int oc = rem / 768;
  int kk = rem - oc * 768;
  int ks = kk >> 8, ii = kk & 255;
  o[idx] = f2b(w[j * 196608 + oc * 768 + ii * 3 + ks]);
}

// ---------------- neighbor mean aggregation (R4-measured form: fp32 in, bf16 out) ----------------
__global__ __launch_bounds__(64) void agg_kernel(const float* __restrict__ h,
                                                 const int* __restrict__ rowptr,
                                                 const int* __restrict__ col,
                                                 const float* __restrict__ invdeg,
                                                 ushort* __restrict__ aggb) {
  int n = blockIdx.x;
  int t = threadIdx.x;
  int s = rowptr[n], e = rowptr[n + 1];
  float4 acc = make_float4(0.f, 0.f, 0.f, 0.f);
  for (int j = s; j < e; ++j) {
    int c = col[j];
    const float4 v = *(const float4*)(h + (size_t)c * HH + t * 4);
    acc.x += v.x; acc.y += v.y; acc.z += v.z; acc.w += v.w;
  }
  float id = invdeg[n];
  ushort4 w;
  w.x = f2b(acc.x * id); w.y = f2b(acc.y * id);
  w.z = f2b(acc.z * id); w.w = f2b(acc.w * id);
  *(ushort4*)(aggb + (size_t)n * HH + t * 4) = w;
}

// ---------------- bf16 MFMA GEMM, BM=64 BN=128 BK=32 (R4-measured form) ----------------
__global__ __launch_bounds__(256) void gemm_mfma(
    const ushort* __restrict__ A0, const ushort* __restrict__ A1,
    const ushort* __restrict__ B0, const ushort* __restrict__ B1,
    const float* __restrict__ bias, float* __restrict__ Cf, ushort* __restrict__ Cb,
    int M, int Nn, int K, int KHA, int KHB, int relu) {
  __shared__ ushort Alds[64][40];
  __shared__ ushort Blds[128][40];
  int t = threadIdx.x;
  int w = t >> 6, l = t & 63, quad = l >> 4, lr = l & 15;
  int wm = w & 1, wn = w >> 1;
  int m0 = blockIdx.x * 64, n0 = blockIdx.y * 128;
  int sr = t >> 2, sc8 = (t & 3) * 8;
  f32x4_t acc[2][4];
#pragma unroll
  for (int s = 0; s < 2; ++s)
#pragma unroll
    for (int q = 0; q < 4; ++q) acc[s][q] = (f32x4_t){0.f, 0.f, 0.f, 0.f};

  for (int k0 = 0; k0 < K; k0 += 32) {
    int kk = k0 + sc8;
    const ushort* ap = (kk < KHA) ? (A0 + (size_t)(m0 + sr) * KHA + kk)
                                  : (A1 + (size_t)(m0 + sr) * (K - KHA) + (kk - KHA));
    uint4 av = *(const uint4*)ap;
    const ushort* bp0 = (kk < KHB) ? (B0 + (size_t)(n0 + sr) * KHB + kk)
                                   : (B1 + (size_t)(n0 + sr) * (K - KHB) + (kk - KHB));
    uint4 bv0 = *(const uint4*)bp0;
    const ushort* bp1 = (kk < KHB) ? (B0 + (size_t)(n0 + 64 + sr) * KHB + kk)
                                   : (B1 + (size_t)(n0 + 64 + sr) * (K - KHB) + (kk - KHB));
    uint4 bv1 = *(const uint4*)bp1;
    __syncthreads();
    *(uint4*)&Alds[sr][sc8] = av;
    *(uint4*)&Blds[sr][sc8] = bv0;
    *(uint4*)&Blds[64 + sr][sc8] = bv1;
    __syncthreads();
    bf16x8_t af[2], bf[4];
#pragma unroll
    for (int s = 0; s < 2; ++s)
      af[s] = *(const bf16x8_t*)&Alds[wm * 32 + s * 16 + lr][quad * 8];
#pragma unroll
    for (int q = 0; q < 4; ++q)
      bf[q] = *(const bf16x8_t*)&Blds[wn * 64 + q * 16 + lr][quad * 8];
#pragma unroll
    for (int s = 0; s < 2; ++s)
#pragma unroll
      for (int q = 0; q < 4; ++q)
        acc[s][q] = __builtin_amdgcn_mfma_f32_16x16x32_bf16(af[s], bf[q], acc[s][q], 0, 0, 0);
  }
#pragma unroll
  for (int s = 0; s < 2; ++s) {
#pragma unroll
    for (int q = 0; q < 4; ++q) {
      int n = n0 + wn * 64 + q * 16 + lr;
      float bb = bias[n];
#pragma unroll
      for (int r = 0; r < 4; ++r) {
        int m = m0 + wm * 32 + s * 16 + quad * 4 + r;
        float v = acc[s][q][r] + bb;
        if (relu) v = fmaxf(v, 0.f);
        if (Cf) Cf[(size_t)m * Nn + n] = v;
        if (Cb) Cb[(size_t)m * Nn + n] = f2b(v);
      }
    }
  }
}

// ---------------- conv1d(k=3,pad=1) as MFMA GEMM, relu(x+b), fp32 out (R4 form) ----------------
__global__ __launch_bounds__(256) void gemm_conv_mfma(
    const ushort* __restrict__ Ab, const ushort* __restrict__ B,
    const float* __restrict__ bias, float* __restrict__ Cf) {
  __shared__ ushort Alds[64][40];
  __shared__ ushort Blds[128][40];
  int t = threadIdx.x;
  int w = t >> 6, l = t & 63, quad = l >> 4, lr = l & 15;
  int wm = w & 1, wn = w >> 1;
  int m0 = blockIdx.x * 64, n0 = blockIdx.y * 128;
  int sr = t >> 2, sc8 = (t & 3) * 8;
  f32x4_t acc[2][4];
#pragma unroll
  for (int s = 0; s < 2; ++s)
#pragma unroll
    for (int q = 0; q < 4; ++q) acc[s][q] = (f32x4_t){0.f, 0.f, 0.f, 0.f};

  for (int k0 = 0; k0 < 768; k0 += 32) {
    int kk = k0 + sc8;
    int ks = kk >> 8, ii = kk & 255;
    int nr = m0 + sr + ks - 1;
    uint4 av = make_uint4(0u, 0u, 0u, 0u);
    if (nr >= 0 && nr < NN) av = *(const uint4*)(Ab + (size_t)nr * HH + ii);
    uint4 bv0 = *(const uint4*)(B + (size_t)(n0 + sr) * 768 + kk);
    uint4 bv1 = *(const uint4*)(B + (size_t)(n0 + 64 + sr) * 768 + kk);
    __syncthreads();
    *(uint4*)&Alds[sr][sc8] = av;
    *(uint4*)&Blds[sr][sc8] = bv0;
    *(uint4*)&Blds[64 + sr][sc8] = bv1;
    __syncthreads();
    bf16x8_t af[2], bf[4];
#pragma unroll
    for (int s = 0; s < 2; ++s)
      af[s] = *(const bf16x8_t*)&Alds[wm * 32 + s * 16 + lr][quad * 8];
#pragma unroll
    for (int q = 0; q < 4; ++q)
      bf[q] = *(const bf16x8_t*)&Blds[wn * 64 + q * 16 + lr][quad * 8];
#pragma unroll
    for (int s = 0; s < 2; ++s)
#pragma unroll
      for (int q = 0; q < 4; ++q)
        acc[s][q] = __builtin_amdgcn_mfma_f32_16x16x32_bf16(af[s], bf[q], acc[s][q], 0, 0, 0);
  }
#pragma unroll
  for (int s = 0; s < 2; ++s) {
#pragma unroll
    for (int q = 0; q < 4; ++q) {
      int n = n0 + wn * 64 + q * 16 + lr;
      float bb = bias[n];
#pragma unroll
      for (int r = 0; r < 4; ++r) {
        int m = m0 + wm * 32 + s * 16 + quad * 4 + r;
        Cf[(size_t)m * HH + n] = fmaxf(acc[s][q][r] + bb, 0.f);
      }
    }
  }
}

// ---------------- fp32 tiled GEMM (fuse head only, R4-measured form) ----------------
__global__ __launch_bounds__(256) void gemm_std(
    const float* __restrict__ A0, const float* __restrict__ B0,
    const float* __restrict__ bias, float* __restrict__ C,
    int M, int Nn, int K) {
  __shared__ float As[16][68];
  __shared__ float Bs[16][68];
  int t = threadIdx.x;
  int m0 = blockIdx.x * 64, n0 = blockIdx.y * 64;
  int ty = t >> 4, tx = t & 15;
  int lr = t >> 2, lc4 = (t & 3) * 4;
  float acc[4][4] = {};
  for (int k0 = 0; k0 < K; k0 += 16) {
    int kk = k0 + lc4;
    float4 va = *(const float4*)(A0 + (size_t)(m0 + lr) * K + kk);
    As[lc4 + 0][lr] = va.x; As[lc4 + 1][lr] = va.y;
    As[lc4 + 2][lr] = va.z; As[lc4 + 3][lr] = va.w;
    float4 vb = *(const float4*)(B0 + (size_t)(n0 + lr) * K + kk);
    Bs[lc4 + 0][lr] = vb.x; Bs[lc4 + 1][lr] = vb.y;
    Bs[lc4 + 2][lr] = vb.z; Bs[lc4 + 3][lr] = vb.w;
    __syncthreads();
#pragma unroll
    for (int k = 0; k < 16; ++k) {
      float4 a4 = *(const float4*)&As[k][4 * ty];
      float4 b4 = *(const float4*)&Bs[k][4 * tx];
      float av[4] = {a4.x, a4.y, a4.z, a4.w};
      float bv[4] = {b4.x, b4.y, b4.z, b4.w};
#pragma unroll
      for (int i = 0; i < 4; ++i)
#pragma unroll
        for (int j = 0; j < 4; ++j) acc[i][j] += av[i] * bv[j];
    }
    __syncthreads();
  }
#pragma unroll
  for (int i = 0; i < 4; ++i) {
    int m = m0 + 4 * ty + i;
    float o[4];
#pragma unroll
    for (int j = 0; j < 4; ++j) o[j] = acc[i][j] + bias[n0 + 4 * tx + j];
    float4 o4 = make_float4(o[0], o[1], o[2], o[3]);
    *(float4*)(C + (size_t)m * Nn + n0 + 4 * tx) = o4;
  }
}

// ---------------- fused LayerNorm, block-per-row (R4-measured form), dual output ----------------
__global__ __launch_bounds__(256) void ln_fuse(
    const float* __restrict__ x, const float* __restrict__ g, const float* __restrict__ b,
    const float* __restrict__ res, float* __restrict__ outf, ushort* __restrict__ outb,
    int D, int do_ln, int relu_res) {
  int row = blockIdx.x, t = threadIdx.x;
  int nv = D >> 8;
  float vals[2];
  float s = 0.f, sq = 0.f;
  for (int u = 0; u < nv; ++u) {
    float v = x[(size_t)row * D + t + (u << 8)];
    vals[u] = v; s += v; sq += v * v;
  }
  __shared__ float red[8];
  float m = 0.f, inv = 1.f;
  if (do_ln) {
    for (int off = 32; off >= 1; off >>= 1) {
      s += __shfl_xor(s, off);
      sq += __shfl_xor(sq, off);
    }
    int wid = t >> 6;
    if ((t & 63) == 0) { red[wid] = s; red[4 + wid] = sq; }
    __syncthreads();
    if (t == 0) {
      float S = red[0] + red[1] + red[2] + red[3];
      float Q = red[4] + red[5] + red[6] + red[7];
      float mm = S / D;
      float vv = Q / D - mm * mm;
      red[0] = mm;
      red[1] = rsqrtf(vv + LN_EPS);
    }
    __syncthreads();
    m = red[0]; inv = red[1];
  }
  for (int u = 0; u < nv; ++u) {
    int c = t + (u << 8);
    float y = vals[u];
    if (do_ln) y = (y - m) * inv * g[c] + b[c];
    if (relu_res) y = fmaxf(y, 0.f) + res[(size_t)row * D + c];
    if (outf) outf[(size_t)row * D + c] = y;
    if (outb) outb[(size_t)row * D + c] = f2b(y);
  }
}

// ---------------- V transpose: qkvb[n][1024+dg] -> Vt[dg][n] (bf16) ----------------
__global__ __launch_bounds__(256) void vtrans(const ushort* __restrict__ qkvb,
                                              ushort* __restrict__ Vt) {
  __shared__ ushort tile[32][34];
  int t = threadIdx.x;
  int n0 = blockIdx.x * 32, d0 = blockIdx.y * 32;
  int tx = t & 31, ty = t >> 5;
#pragma unroll
  for (int u = 0; u < 4; ++u) {
    int r = ty + 8 * u;
    tile[r][tx] = qkvb[(size_t)(n0 + r) * 1536 + 1024 + d0 + tx];
  }
  __syncthreads();
#pragma unroll
  for (int u = 0; u < 4; ++u) {
    int dy = ty + 8 * u;
    Vt[(size_t)(d0 + dy) * NN + n0 + tx] = tile[tx][dy];
  }
}

// ---------------- attn v2: direct-global B-frags, barrier-free, 32 q-rows/wave ----------------
// Grid (NN/64, 4 heads), 128 threads (2 waves); wave w handles rows q0 = blk*64 + w*32.
// K/V B-fragments are 16B-contiguous in qkvb / Vt -> loaded straight from global (VMEM pipe,
// L1/L2-resident), eliminating all K/V LDS staging and every __syncthreads.
// Denominator via ones-column MFMA (P x ones = rowsum). Only P's C->A transform uses LDS (per-wave).
__global__ __launch_bounds__(128, 1) void attn_mfma(const ushort* __restrict__ qkvb,
                                                    const ushort* __restrict__ Vt,
                                                    ushort* __restrict__ Ob) {
  __shared__ ushort Plds[2][32][72];   // per-wave strip: 32 q-rows x 64 kv (pitch 72)

  int t = threadIdx.x;
  int w = t >> 6, l = t & 63;
  int quad = l >> 4, lr = l & 15;
  int head = blockIdx.y;
  int q0 = blockIdx.x * 64 + w * 32;

  // Q A-frags: rows q0 + s*16 + lr, k = ks*32 + quad*8 + j
  bf16x8_t qf[2][4];
#pragma unroll
  for (int s = 0; s < 2; ++s)
#pragma unroll
    for (int ks = 0; ks < 4; ++ks)
      qf[s][ks] = *(const bf16x8_t*)(qkvb + (size_t)(q0 + s * 16 + lr) * 1536 + head * 128 +
                                     ks * 32 + quad * 8);

  // ones B-frag: B[n=0][k]=1 else 0  ->  D[m][0] = sum_k A[m][k]
  bf16x8_t onesf;
  {
    short ov = (lr == 0) ? (short)0x3F80 : (short)0;
#pragma unroll
    for (int j = 0; j < 8; ++j) onesf[j] = ov;
  }

  f32x4_t of[2][8];
  f32x4_t oden[2];
#pragma unroll
  for (int s = 0; s < 2; ++s) {
    oden[s] = (f32x4_t){0.f, 0.f, 0.f, 0.f};
#pragma unroll
    for (int dt = 0; dt < 8; ++dt) of[s][dt] = (f32x4_t){0.f, 0.f, 0.f, 0.f};
  }

  const ushort* kbase = qkvb + 512 + head * 128 + quad * 8;
  const ushort* vbase = Vt + (size_t)head * 128 * NN + quad * 8;

  for (int kt = 0; kt < NN / 64; ++kt) {
    int k0 = kt * 64;

    // S = Q K^T : K B-frag [n=kv(ct*16+lr)][k=ks*32+quad*8] direct from global
    f32x4_t sf[2][4];
#pragma unroll
    for (int s = 0; s < 2; ++s)
#pragma unroll
      for (int ct = 0; ct < 4; ++ct) sf[s][ct] = (f32x4_t){0.f, 0.f, 0.f, 0.f};
#pragma unroll
    for (int ks = 0; ks < 4; ++ks) {
#pragma unroll
      for (int ct = 0; ct < 4; ++ct) {
        bf16x8_t kf = *(const bf16x8_t*)(kbase + (size_t)(k0 + ct * 16 + lr) * 1536 + ks * 32);
        sf[0][ct] = __builtin_amdgcn_mfma_f32_16x16x32_bf16(qf[0][ks], kf, sf[0][ct], 0, 0, 0);
        sf[1][ct] = __builtin_amdgcn_mfma_f32_16x16x32_bf16(qf[1][ks], kf, sf[1][ct], 0, 0, 0);
      }
    }

    // softmax (global shift), write P strip in C-layout
#pragma unroll
    for (int s = 0; s < 2; ++s)
#pragma unroll
      for (int ct = 0; ct < 4; ++ct)
#pragma unroll
        for (int r = 0; r < 4; ++r) {
          float e = __expf(sf[s][ct][r] * ATT_SCALE - ATT_SHIFT);
          Plds[w][s * 16 + quad * 4 + r][ct * 16 + lr] = f2b(e);
        }

    // O += P V (+ den += P 1) : V B-frag [n=d(dt*16+lr)][k=ks2*32+quad*8] direct from global
#pragma unroll
    for (int ks2 = 0; ks2 < 2; ++ks2) {
      bf16x8_t pf0 = *(const bf16x8_t*)&Plds[w][lr][ks2 * 32 + quad * 8];
      bf16x8_t pf1 = *(const bf16x8_t*)&Plds[w][16 + lr][ks2 * 32 + quad * 8];
      oden[0] = __builtin_amdgcn_mfma_f32_16x16x32_bf16(pf0, onesf, oden[0], 0, 0, 0);
      oden[1] = __builtin_amdgcn_mfma_f32_16x16x32_bf16(pf1, onesf, oden[1], 0, 0, 0);
#pragma unroll
      for (int dt = 0; dt < 8; ++dt) {
        bf16x8_t vf = *(const bf16x8_t*)(vbase + (size_t)(dt * 16 + lr) * NN + k0 + ks2 * 32);
        of[0][dt] = __builtin_amdgcn_mfma_f32_16x16x32_bf16(pf0, vf, of[0][dt], 0, 0, 0);
        of[1][dt] = __builtin_amdgcn_mfma_f32_16x16x32_bf16(pf1, vf, of[1][dt], 0, 0, 0);
      }
    }
  }

  // den for row (s, quad*4+r) lives in lane quad*16 (col 0), reg r -> broadcast to quad group
  float inv[2][4];
#pragma unroll
  for (int s = 0; s < 2; ++s)
#pragma unroll
    for (int r = 0; r < 4; ++r) {
      float d = __shfl(oden[s][r], (l & 48));
      inv[s][r] = 1.0f / d;
    }
#pragma unroll
  for (int s = 0; s < 2; ++s)
#pragma unroll
    for (int dt = 0; dt < 8; ++dt)
#pragma unroll
      for (int r = 0; r < 4; ++r) {
        int row = q0 + s * 16 + quad * 4 + r;
        Ob[(size_t)row * 512 + head * 128 + dt * 16 + lr] = f2b(of[s][dt][r] * inv[s][r]);
      }
}

// ---------------- launch (R4-measured sequence, attn swapped) ----------------
extern "C" void kernel_launch(void* const* d_in, const int* in_sizes, int n_in,
                              void* d_out, int out_size, void* d_ws, size_t ws_size,
                              hipStream_t stream) {
  const float* x          = (const float*)d_in[0];
  const int*   ei         = (const int*)d_in[1];
  const float* sage_wl    = (const float*)d_in[2];
  const float* sage_wr    = (const float*)d_in[3];
  const float* sage_bl    = (const float*)d_in[4];
  const float* ln_g       = (const float*)d_in[5];
  const float* ln_b       = (const float*)d_in[6];
  const float* conv_w     = (const float*)d_in[7];
  const float* conv_b     = (const float*)d_in[8];
  const float* cnorm_g    = (const float*)d_in[9];
  const float* cnorm_b    = (const float*)d_in[10];
  const float* in_proj_w  = (const float*)d_in[11];
  const float* in_proj_b  = (const float*)d_in[12];
  const float* out_proj_w = (const float*)d_in[13];
  const float* out_proj_b = (const float*)d_in[14];
  const float* anorm_g    = (const float*)d_in[15];
  const float* anorm_b    = (const float*)d_in[16];
  const float* fuse_w     = (const float*)d_in[17];
  const float* fuse_b     = (const float*)d_in[18];
  float* out = (float*)d_out;

  // Workspace map (R4-measured, max ~42 MB):
  //  0..1  CSR | 1..5 h fp32 | 5..7 hb | 7..9 aggb | 9..13 tmp fp32 | 13..15 c0b | 15..17 c1b
  //  17..29 qkvb (op fp32 17..25 reuses after attn) | 29..33 Vt | 33..37 aob | 37..42 weights
  char* ws = (char*)d_ws;
  const size_t MB = 1 << 20;
  int*    rowptr = (int*)(ws + 0);
  int*    cnt    = (int*)(ws + 65536);
  int*    col    = (int*)(ws + 131072);
  float*  invdeg = (float*)(ws + 786432);
  float*  h    = (float*)(ws + 1 * MB);
  ushort* hb   = (ushort*)(ws + 5 * MB);
  ushort* aggb = (ushort*)(ws + 7 * MB);
  float*  tmp  = (float*)(ws + 9 * MB);
  ushort* c0b  = (ushort*)(ws + 13 * MB);
  ushort* c1b  = (ushort*)(ws + 15 * MB);
  ushort* qkvb = (ushort*)(ws + 17 * MB);
  float*  op   = (float*)(ws + 17 * MB);   // reuses qkvb after attention
  ushort* Vt   = (ushort*)(ws + 29 * MB);
  ushort* aob  = (ushort*)(ws + 33 * MB);
  ushort* wlb  = (ushort*)(ws + 37 * MB);
  ushort* wrb  = (ushort*)(ws + 37 * MB + 786432);
  ushort* cvb  = (ushort*)(ws + 37 * MB + 1572864);
  ushort* ipb  = (ushort*)(ws + 37 * MB + 2752512);
  ushort* opb  = (ushort*)(ws + 37 * MB + 4325376);

  // weight casts
  castw<<<(6 * 256 * 256) / 1024, 256, 0, stream>>>(sage_wl, wlb);
  castw<<<(6 * 256 * 256) / 1024, 256, 0, stream>>>(sage_wr, wrb);
  castconv<<<(3 * 256 * 768) / 256, 256, 0, stream>>>(conv_w, cvb);
  castw<<<(1536 * 512) / 1024, 256, 0, stream>>>(in_proj_w, ipb);
  castw<<<(512 * 512) / 1024, 256, 0, stream>>>(out_proj_w, opb);

  // CSR
  hipMemsetAsync(cnt, 0, NN * sizeof(int), stream);
  hist_kernel<<<EE / 256, 256, 0, stream>>>(ei, cnt);
  scan_kernel<<<1, 1024, 0, stream>>>(cnt, rowptr, invdeg);
  fill_kernel<<<EE / 256, 256, 0, stream>>>(ei, cnt, col);
  hipMemcpyAsync(h, x, (size_t)NN * HH * sizeof(float), hipMemcpyDeviceToDevice, stream);
  castw<<<(NN * HH) / 1024, 256, 0, stream>>>(x, hb);

  // GNN: 6 SAGE layers
  for (int i = 0; i < 6; ++i) {
    agg_kernel<<<NN, 64, 0, stream>>>(h, rowptr, col, invdeg, aggb);
    gemm_mfma<<<dim3(64, 2), 256, 0, stream>>>(
        aggb, hb, wlb + (size_t)i * HH * HH, wrb + (size_t)i * HH * HH,
        sage_bl + i * HH, tmp, nullptr, NN, HH, 512, 256, 256, 0);
    int do_ln = (i < 5) ? 1 : 0;
    const float* gp = do_ln ? (ln_g + i * HH) : ln_g;
    const float* bp = do_ln ? (ln_b + i * HH) : ln_b;
    ln_fuse<<<NN, 256, 0, stream>>>(tmp, gp, bp, h, h, hb, HH, do_ln, 1);
  }

  // CNN: 3 conv layers (bf16 chain)
  const ushort* cin = hb;
  ushort* couts[3] = {c0b, c1b, c0b};
  for (int j = 0; j < 3; ++j) {
    gemm_conv_mfma<<<dim3(64, 2), 256, 0, stream>>>(
        cin, cvb + (size_t)j * HH * 768, conv_b + j * HH, tmp);
    ln_fuse<<<NN, 256, 0, stream>>>(tmp, cnorm_g + j * HH, cnorm_b + j * HH,
                                    nullptr, nullptr, couts[j], HH, 1, 0);
    cin = couts[j];
  }

  // attention
  gemm_mfma<<<dim3(64, 12), 256, 0, stream>>>(
      hb, c0b, ipb, nullptr, in_proj_b, nullptr, qkvb, NN, 1536, 512, 256, 512, 0);
  vtrans<<<dim3(NN / 32, 512 / 32), 256, 0, stream>>>(qkvb, Vt);
  attn_mfma<<<dim3(NN / 64, 4), 128, 0, stream>>>(qkvb, Vt, aob);

  gemm_mfma<<<dim3(64, 4), 256, 0, stream>>>(
      aob, nullptr, opb, nullptr, out_proj_b, op, nullptr, NN, 512, 512, 512, 512, 0);
  ln_fuse<<<NN, 256, 0, stream>>>(op, anorm_g, anorm_b, nullptr, op, nullptr, 512, 1, 0);
  gemm_std<<<dim3(64, 1), 256, 0, stream>>>(op, fuse_w, fuse_b, out, NN, 64, 512);
}